// Round 1
// baseline (1269.342 us; speedup 1.0000x reference)
//
#include <hip/hip_runtime.h>
#include <hip/hip_bf16.h>

// Problem dims (fixed by reference)
#define T_DIM 256
#define B_DIM 128
#define C_DIM 1024
#define H_DIM 1024
#define L_DIM 6
#define NC_DIM 1000
#define M_DIM (T_DIM * B_DIM)    // 32768 rows for the big GEMM
#define BH_DIM (B_DIM * H_DIM)   // 131072 independent recurrences

typedef __attribute__((ext_vector_type(8))) short bf16x8;
typedef __attribute__((ext_vector_type(4))) float f32x4;

__device__ __forceinline__ float bf2f(unsigned short u) {
  union { unsigned int i; float f; } v; v.i = ((unsigned int)u) << 16; return v.f;
}
__device__ __forceinline__ unsigned short f2bf(float f) {
  union { float f; unsigned int i; } v; v.f = f;
  unsigned int r = v.i + 0x7fffu + ((v.i >> 16) & 1u);  // RNE
  return (unsigned short)(r >> 16);
}

__device__ __forceinline__ void gload_lds16(const void* g, void* l) {
  __builtin_amdgcn_global_load_lds(
      (const __attribute__((address_space(1))) unsigned int*)g,
      (__attribute__((address_space(3))) unsigned int*)l, 16, 0, 0);
}

// ---------------- x f32 -> bf16 convert (vectorized) ----------------
__global__ __launch_bounds__(256) void f32_to_bf16_kernel(
    const float* __restrict__ in, unsigned short* __restrict__ out, int n4) {
  int stride = gridDim.x * blockDim.x;
  for (int i = blockIdx.x * blockDim.x + threadIdx.x; i < n4; i += stride) {
    float4 v = ((const float4*)in)[i];
    ushort4 o;
    o.x = f2bf(v.x); o.y = f2bf(v.y); o.z = f2bf(v.z); o.w = f2bf(v.w);
    ((ushort4*)out)[i] = o;
  }
}

// ---------------- W (L,C,H) f32 -> Wt (L,H,C) bf16 transpose ----------------
__global__ __launch_bounds__(256) void wtrans_kernel(
    const float* __restrict__ W, unsigned short* __restrict__ Wt) {
  __shared__ float tile[32][33];
  int l = blockIdx.z;
  const float* Wl = W + (size_t)l * C_DIM * H_DIM;
  unsigned short* Wtl = Wt + (size_t)l * C_DIM * H_DIM;
  int h0 = blockIdx.x * 32, c0 = blockIdx.y * 32;
  int tx = threadIdx.x, ty = threadIdx.y;  // 32 x 8
#pragma unroll
  for (int i = 0; i < 32; i += 8)
    tile[ty + i][tx] = Wl[(size_t)(c0 + ty + i) * H_DIM + h0 + tx];
  __syncthreads();
#pragma unroll
  for (int i = 0; i < 32; i += 8)
    Wtl[(size_t)(h0 + ty + i) * C_DIM + c0 + tx] = f2bf(tile[tx][ty + i]);
}

// ---------------- GEMM: Z(f32, MxN) = A(bf16, MxK) * Wt(bf16, NxK)^T ----------------
// m97 structure: 128x128 tile, BK=32, 4 waves (2x2), 4x4 16x16x32 frags/wave,
// global_load_lds width 16, single-buffered LDS, XCD-swizzled grid.
#define BM 128
#define BN 128
#define BK 32

__global__ __launch_bounds__(256) void gemm_kernel(
    const unsigned short* __restrict__ A, const unsigned short* __restrict__ Bt,
    float* __restrict__ Cc) {
  __shared__ unsigned short As[BM * BK];
  __shared__ unsigned short Bs[BN * BK];
  // 2048 blocks, 8 XCDs -> bijective swizzle: XCD x gets contiguous 256 tiles
  int bid = blockIdx.x;
  int swz = (bid & 7) * 256 + (bid >> 3);
  int tm = swz >> 3;  // 0..255  (M tile)
  int tn = swz & 7;   // 0..7    (N tile)
  int tid = threadIdx.x;
  int wv = tid >> 6, ln = tid & 63;
  int wm = wv >> 1, wn = wv & 1;  // 2x2 wave grid
  int lr = ln & 15;               // fragment row/col
  int lk = (ln >> 4) << 3;        // fragment k offset

  f32x4 acc[4][4];
  f32x4 zero = {0.f, 0.f, 0.f, 0.f};
#pragma unroll
  for (int i = 0; i < 4; ++i)
#pragma unroll
    for (int j = 0; j < 4; ++j) acc[i][j] = zero;

  const size_t K = C_DIM;
  // staging: tile = 8192B; per wave-inst = 64 lanes * 16B = 1024B; 8 chunks, 2 per wave
  int lin0 = wv * 1024;
  int lin1 = (4 + wv) * 1024;
  int e0 = (lin0 >> 1) + ln * 8;
  int e1 = (lin1 >> 1) + ln * 8;
  int r0s = e0 >> 5, c0s = e0 & 31;
  int r1s = e1 >> 5, c1s = e1 & 31;
  const unsigned short* Abase = A + (size_t)(tm * BM) * K;
  const unsigned short* Bbase = Bt + (size_t)(tn * BN) * K;

  for (int k0 = 0; k0 < C_DIM; k0 += BK) {
    gload_lds16(Abase + (size_t)r0s * K + k0 + c0s, (char*)As + lin0);
    gload_lds16(Abase + (size_t)r1s * K + k0 + c1s, (char*)As + lin1);
    gload_lds16(Bbase + (size_t)r0s * K + k0 + c0s, (char*)Bs + lin0);
    gload_lds16(Bbase + (size_t)r1s * K + k0 + c1s, (char*)Bs + lin1);
    __syncthreads();
    bf16x8 af[4], bfr[4];
#pragma unroll
    for (int f = 0; f < 4; ++f)
      af[f] = *(const bf16x8*)&As[(wm * 64 + f * 16 + lr) * BK + lk];
#pragma unroll
    for (int f = 0; f < 4; ++f)
      bfr[f] = *(const bf16x8*)&Bs[(wn * 64 + f * 16 + lr) * BK + lk];
#pragma unroll
    for (int i = 0; i < 4; ++i)
#pragma unroll
      for (int j = 0; j < 4; ++j)
        acc[i][j] = __builtin_amdgcn_mfma_f32_16x16x32_bf16(af[i], bfr[j], acc[i][j], 0, 0, 0);
    __syncthreads();
  }

  // C/D layout (m89-verified): col = lane&15, row = (lane>>4)*4 + reg
  int rr = tm * BM + wm * 64 + ((ln >> 4) << 2);
  int cc = tn * BN + wn * 64 + lr;
#pragma unroll
  for (int i = 0; i < 4; ++i)
#pragma unroll
    for (int j = 0; j < 4; ++j) {
      float* cp = Cc + (size_t)(rr + i * 16) * H_DIM + cc + j * 16;
#pragma unroll
      for (int r = 0; r < 4; ++r) cp[(size_t)r * H_DIM] = acc[i][j][r];
    }
}

// ---------------- BN stats: per-channel partial sums (deterministic 2-stage) ----------------
__global__ __launch_bounds__(256) void bn_stats_kernel(
    const float* __restrict__ Z, float* __restrict__ psum, float* __restrict__ psqs) {
  int blk = blockIdx.x, tid = threadIdx.x;  // 256 blocks x 128 rows each
  const float4* base = (const float4*)(Z + (size_t)blk * 128 * H_DIM);
  float4 s = {0, 0, 0, 0}, q = {0, 0, 0, 0};
  for (int r = 0; r < 128; ++r) {
    float4 v = base[(size_t)r * (H_DIM / 4) + tid];
    s.x += v.x; s.y += v.y; s.z += v.z; s.w += v.w;
    q.x += v.x * v.x; q.y += v.y * v.y; q.z += v.z * v.z; q.w += v.w * v.w;
  }
  ((float4*)(psum + (size_t)blk * H_DIM))[tid] = s;
  ((float4*)(psqs + (size_t)blk * H_DIM))[tid] = q;
}

__global__ __launch_bounds__(256) void bn_finalize_kernel(
    const float* __restrict__ psum, const float* __restrict__ psqs,
    const float* __restrict__ gamma, const float* __restrict__ beta,
    float* __restrict__ ss) {
  int c = blockIdx.x * blockDim.x + threadIdx.x;  // 1024 channels
  float s = 0.f, q = 0.f;
  for (int i = 0; i < 256; ++i) {
    s += psum[(size_t)i * H_DIM + c];
    q += psqs[(size_t)i * H_DIM + c];
  }
  const float invN = 1.0f / (float)M_DIM;
  float mean = s * invN;
  float var = q * invN - mean * mean;
  float sc = gamma[c] * rsqrtf(var + 1e-5f);
  ss[c] = sc;
  ss[H_DIM + c] = beta[c] - mean * sc;
}

// ---------------- fused BN-apply + IndRNN recurrence (writes bf16 activations) ----------------
__global__ __launch_bounds__(256) void bn_recur_kernel(
    const float* __restrict__ Z, const float* __restrict__ ss,
    const float* __restrict__ u, unsigned short* __restrict__ Hout) {
  int i = blockIdx.x * 256 + threadIdx.x;  // 0..BH_DIM-1
  int h = i & (H_DIM - 1);
  float scale = ss[h], shift = ss[H_DIM + h], uu = u[h];
  float hv = 0.f;
#pragma unroll 4
  for (int t = 0; t < T_DIM; ++t) {
    float z = fmaf(Z[(size_t)t * BH_DIM + i], scale, shift);
    hv = fmaxf(fmaf(uu, hv, z), 0.f);
    Hout[(size_t)t * BH_DIM + i] = f2bf(hv);
  }
}

// ---------------- classifier: out(B,NC) = h_last(B,H) @ Wc(H,NC) + bc ----------------
__global__ __launch_bounds__(256) void classifier_kernel(
    const unsigned short* __restrict__ hlast, const float* __restrict__ Wc,
    const float* __restrict__ bc, float* __restrict__ out) {
  __shared__ float hs[H_DIM];
  int b = blockIdx.y;
  int n = blockIdx.x * 256 + threadIdx.x;
  for (int k = threadIdx.x; k < H_DIM; k += 256)
    hs[k] = bf2f(hlast[(size_t)b * H_DIM + k]);
  __syncthreads();
  if (n < NC_DIM) {
    float acc = bc[n];
#pragma unroll 8
    for (int k = 0; k < H_DIM; ++k)
      acc = fmaf(hs[k], Wc[(size_t)k * NC_DIM + n], acc);
    out[(size_t)b * NC_DIM + n] = acc;
  }
}

extern "C" void kernel_launch(void* const* d_in, const int* in_sizes, int n_in,
                              void* d_out, int out_size, void* d_ws, size_t ws_size,
                              hipStream_t stream) {
  const float* x     = (const float*)d_in[0];
  const float* W     = (const float*)d_in[1];
  // d_in[2] = b: mathematically cancels under BatchNorm (shift-invariant) -> unused
  const float* gamma = (const float*)d_in[3];
  const float* beta  = (const float*)d_in[4];
  const float* u     = (const float*)d_in[5];
  const float* Wc    = (const float*)d_in[6];
  const float* bc    = (const float*)d_in[7];
  float* out = (float*)d_out;

  const size_t CH = (size_t)C_DIM * H_DIM;        // 1M
  const size_t MH = (size_t)M_DIM * H_DIM;        // 33.5M
  char* p = (char*)d_ws;
  unsigned short* Wt = (unsigned short*)p; p += L_DIM * CH * sizeof(unsigned short); // 12 MB
  unsigned short* Ha = (unsigned short*)p; p += MH * sizeof(unsigned short);         // 64 MB
  unsigned short* Hb = (unsigned short*)p; p += MH * sizeof(unsigned short);         // 64 MB
  float* Z    = (float*)p; p += MH * sizeof(float);                                  // 128 MB
  float* psum = (float*)p; p += 256 * H_DIM * sizeof(float);                         // 1 MB
  float* psqs = (float*)p; p += 256 * H_DIM * sizeof(float);                         // 1 MB
  float* ss   = (float*)p; p += 2 * H_DIM * sizeof(float);

  // 1. x -> bf16
  f32_to_bf16_kernel<<<2048, 256, 0, stream>>>(x, Ha, (int)(MH / 4));
  // 2. all 6 weight transposes
  wtrans_kernel<<<dim3(H_DIM / 32, C_DIM / 32, L_DIM), dim3(32, 8), 0, stream>>>(W, Wt);

  unsigned short* cur = Ha;
  unsigned short* nxt = Hb;
  for (int l = 0; l < L_DIM; ++l) {
    gemm_kernel<<<(M_DIM / BM) * (H_DIM / BN), 256, 0, stream>>>(cur, Wt + (size_t)l * CH, Z);
    bn_stats_kernel<<<256, 256, 0, stream>>>(Z, psum, psqs);
    bn_finalize_kernel<<<4, 256, 0, stream>>>(psum, psqs, gamma + (size_t)l * H_DIM,
                                              beta + (size_t)l * H_DIM, ss);
    bn_recur_kernel<<<BH_DIM / 256, 256, 0, stream>>>(Z, ss, u + (size_t)l * H_DIM, nxt);
    unsigned short* tmp = cur; cur = nxt; nxt = tmp;
  }
  // 3. classifier on last timestep of final layer
  classifier_kernel<<<dim3(4, B_DIM), 256, 0, stream>>>(
      cur + (size_t)(T_DIM - 1) * BH_DIM, Wc, bc, out);
}

// Round 2
// 887.491 us; speedup vs baseline: 1.4303x; 1.4303x over previous
//
#include <hip/hip_runtime.h>
#include <hip/hip_bf16.h>

#define T_DIM 256
#define B_DIM 128
#define C_DIM 1024
#define H_DIM 1024
#define L_DIM 6
#define NC_DIM 1000
#define M_DIM (T_DIM * B_DIM)    // 32768
#define BH_DIM (B_DIM * H_DIM)   // 131072

typedef __attribute__((ext_vector_type(8))) short bf16x8;
typedef __attribute__((ext_vector_type(4))) float f32x4;

__device__ __forceinline__ float bf2f(unsigned short u) {
  union { unsigned int i; float f; } v; v.i = ((unsigned int)u) << 16; return v.f;
}
__device__ __forceinline__ unsigned short f2bf(float f) {
  union { float f; unsigned int i; } v; v.f = f;
  unsigned int r = v.i + 0x7fffu + ((v.i >> 16) & 1u);  // RNE
  return (unsigned short)(r >> 16);
}

__device__ __forceinline__ void gload_lds16(const void* g, void* l) {
  __builtin_amdgcn_global_load_lds(
      (const __attribute__((address_space(1))) unsigned int*)g,
      (__attribute__((address_space(3))) unsigned int*)l, 16, 0, 0);
}

// ---------------- x f32 -> bf16 convert ----------------
__global__ __launch_bounds__(256) void f32_to_bf16_kernel(
    const float* __restrict__ in, unsigned short* __restrict__ out, int n4) {
  int stride = gridDim.x * blockDim.x;
  for (int i = blockIdx.x * blockDim.x + threadIdx.x; i < n4; i += stride) {
    float4 v = ((const float4*)in)[i];
    ushort4 o;
    o.x = f2bf(v.x); o.y = f2bf(v.y); o.z = f2bf(v.z); o.w = f2bf(v.w);
    ((ushort4*)out)[i] = o;
  }
}

// ---------------- W (L,C,H) f32 -> Wt (L,H,C) bf16 ----------------
__global__ __launch_bounds__(256) void wtrans_kernel(
    const float* __restrict__ W, unsigned short* __restrict__ Wt) {
  __shared__ float tile[32][33];
  int l = blockIdx.z;
  const float* Wl = W + (size_t)l * C_DIM * H_DIM;
  unsigned short* Wtl = Wt + (size_t)l * C_DIM * H_DIM;
  int h0 = blockIdx.x * 32, c0 = blockIdx.y * 32;
  int tx = threadIdx.x, ty = threadIdx.y;  // 32 x 8
#pragma unroll
  for (int i = 0; i < 32; i += 8)
    tile[ty + i][tx] = Wl[(size_t)(c0 + ty + i) * H_DIM + h0 + tx];
  __syncthreads();
#pragma unroll
  for (int i = 0; i < 32; i += 8)
    Wtl[(size_t)(h0 + ty + i) * C_DIM + c0 + tx] = f2bf(tile[tx][ty + i]);
}

// ---------------- GEMM 256x256 tile, BK=32, 4-buffer deep pipeline ----------------
// Z(f32, M x H) = A(bf16, M x K) * Wt(bf16, N x K)^T, fused BN partial stats.
// 8 waves (2M x 4N), per-wave 128x64 output (8x4 16x16 frags).
// LDS: 4 buffers x (A 16KB + B 16KB) = 128 KiB, XOR-swizzled (16B chunk ^= row&3).
// Counted vmcnt(8): tiles t+2,t+3 stay in flight across the per-tile barrier.
#define NT 32  // K / 32

__global__ __launch_bounds__(512, 2) void gemm_kernel(
    const unsigned short* __restrict__ A, const unsigned short* __restrict__ Bt,
    float* __restrict__ Z, float* __restrict__ psum, float* __restrict__ psqs) {
  extern __shared__ char lds[];
  int bid = blockIdx.x;              // 512 blocks, %8==0 -> bijective XCD swizzle
  int swz = (bid & 7) * 64 + (bid >> 3);
  int tm = swz >> 2, tn = swz & 3;   // 128 x 4 tiles
  int tid = threadIdx.x;
  int wv = tid >> 6, ln = tid & 63;
  int wm = wv >> 2, wn = wv & 3;     // 2 x 4 wave grid

  // ---- staging precompute (pre-swizzled global source, linear LDS dest) ----
  const char* Asrc = (const char*)A + (size_t)tm * 256 * 2048;   // row stride 2048B
  const char* Bsrc = (const char*)Bt + (size_t)tn * 256 * 2048;
  int p0 = wv * 1024 + ln * 16;          // physical byte (load 0)
  int p1 = 8192 + wv * 1024 + ln * 16;   // physical byte (load 1)
  int l0 = p0 ^ (((p0 >> 6) & 3) << 4);  // involution: chunk ^= row&3
  int l1 = p1 ^ (((p1 >> 6) & 3) << 4);
  int ro0 = (l0 >> 6) * 2048 + (l0 & 63);  // panel byte offset sans k-term
  int ro1 = (l1 >> 6) * 2048 + (l1 & 63);
  int dst0 = wv * 1024;         // wave-uniform LDS dest bases (+ lane*16 by HW)
  int dst1 = 8192 + wv * 1024;

  // swizzled ds_read lane offset: row=(ln&15), chunk=(ln>>4)^(ln&3)
  int laneoff = (ln & 15) * 64 + ((((ln >> 4) ^ ln) & 3) << 4);

  f32x4 acc[8][4];
  f32x4 zero = {0.f, 0.f, 0.f, 0.f};
#pragma unroll
  for (int m = 0; m < 8; ++m)
#pragma unroll
    for (int n = 0; n < 4; ++n) acc[m][n] = zero;

  auto stage = [&](int t) {
    char* ldsb = lds + ((t & 3) * 32768);
    int ko = t * 64;
    gload_lds16(Asrc + ro0 + ko, ldsb + dst0);
    gload_lds16(Asrc + ro1 + ko, ldsb + dst1);
    gload_lds16(Bsrc + ro0 + ko, ldsb + 16384 + dst0);
    gload_lds16(Bsrc + ro1 + ko, ldsb + 16384 + dst1);
  };

  auto body = [&](int t, bool dostage) {
    const char* buf = lds + ((t & 3) * 32768);
    const char* Ab = buf + wm * 8192;
    const char* Bb = buf + 16384 + wn * 4096;
    bf16x8 bf[4], a0[4], a1[4];
#pragma unroll
    for (int n = 0; n < 4; ++n) bf[n] = *(const bf16x8*)(Bb + n * 1024 + laneoff);
#pragma unroll
    for (int m = 0; m < 4; ++m) a0[m] = *(const bf16x8*)(Ab + m * 1024 + laneoff);
#pragma unroll
    for (int m = 0; m < 4; ++m) a1[m] = *(const bf16x8*)(Ab + 4096 + m * 1024 + laneoff);
    if (dostage) stage(t + 3);
    __builtin_amdgcn_s_setprio(1);
#pragma unroll
    for (int m = 0; m < 4; ++m)
#pragma unroll
      for (int n = 0; n < 4; ++n)
        acc[m][n] = __builtin_amdgcn_mfma_f32_16x16x32_bf16(a0[m], bf[n], acc[m][n], 0, 0, 0);
#pragma unroll
    for (int m = 0; m < 4; ++m)
#pragma unroll
      for (int n = 0; n < 4; ++n)
        acc[m + 4][n] = __builtin_amdgcn_mfma_f32_16x16x32_bf16(a1[m], bf[n], acc[m + 4][n], 0, 0, 0);
    __builtin_amdgcn_s_setprio(0);
  };

  // prologue: tiles 0,1,2 in flight (12 loads); wait tile0 (vmcnt 8 = tiles 1,2)
  stage(0); stage(1); stage(2);
  asm volatile("s_waitcnt vmcnt(8)" ::: "memory");
  __builtin_amdgcn_s_barrier();

  for (int t = 0; t < NT - 3; ++t) {   // t = 0..28, stages t+3 <= 31
    body(t, true);
    asm volatile("s_waitcnt vmcnt(8)" ::: "memory");  // tiles t+2,t+3 stay in flight
    __builtin_amdgcn_s_barrier();
  }
  body(NT - 3, false);
  asm volatile("s_waitcnt vmcnt(4)" ::: "memory");
  __builtin_amdgcn_s_barrier();
  body(NT - 2, false);
  asm volatile("s_waitcnt vmcnt(0)" ::: "memory");
  __builtin_amdgcn_s_barrier();
  body(NT - 1, false);

  // ---- epilogue: fused BN partial stats + Z write ----
  // C/D layout: col = ln&15, row = (ln>>4)*4 + reg
  float s[4], q[4];
#pragma unroll
  for (int n = 0; n < 4; ++n) {
    float sv = 0.f, qv = 0.f;
#pragma unroll
    for (int m = 0; m < 8; ++m)
#pragma unroll
      for (int r = 0; r < 4; ++r) {
        float v = acc[m][n][r];
        sv += v; qv += v * v;
      }
    s[n] = sv; q[n] = qv;
  }
#pragma unroll
  for (int n = 0; n < 4; ++n) {
    s[n] += __shfl_xor(s[n], 16); s[n] += __shfl_xor(s[n], 32);
    q[n] += __shfl_xor(q[n], 16); q[n] += __shfl_xor(q[n], 32);
  }
  float* red = (float*)lds;  // [2 stat][2 wm][256 col] = 4 KB (buffer 0, dead)
  if (ln < 16) {
#pragma unroll
    for (int n = 0; n < 4; ++n) {
      red[wm * 256 + wn * 64 + n * 16 + ln] = s[n];
      red[512 + wm * 256 + wn * 64 + n * 16 + ln] = q[n];
    }
  }
  __syncthreads();
  if (tid < 256) {
    psum[(size_t)tm * H_DIM + tn * 256 + tid] = red[tid] + red[256 + tid];
  } else {
    int c = tid - 256;
    psqs[(size_t)tm * H_DIM + tn * 256 + c] = red[512 + c] + red[768 + c];
  }
  // Z stores
  int r0 = tm * 256 + wm * 128 + ((ln >> 4) << 2);
  int c0 = tn * 256 + wn * 64 + (ln & 15);
#pragma unroll
  for (int m = 0; m < 8; ++m)
#pragma unroll
    for (int n = 0; n < 4; ++n) {
      float* zp = Z + (size_t)(r0 + m * 16) * H_DIM + c0 + n * 16;
#pragma unroll
      for (int r = 0; r < 4; ++r) zp[(size_t)r * H_DIM] = acc[m][n][r];
    }
}

// ---------------- BN finalize: sum 128 partials per channel ----------------
__global__ __launch_bounds__(256) void bn_finalize_kernel(
    const float* __restrict__ psum, const float* __restrict__ psqs,
    const float* __restrict__ gamma, const float* __restrict__ beta,
    float* __restrict__ ss) {
  int c = blockIdx.x * blockDim.x + threadIdx.x;
  float s = 0.f, q = 0.f;
  for (int i = 0; i < 128; ++i) {
    s += psum[(size_t)i * H_DIM + c];
    q += psqs[(size_t)i * H_DIM + c];
  }
  const float invN = 1.0f / (float)M_DIM;
  float mean = s * invN;
  float var = q * invN - mean * mean;
  float sc = gamma[c] * rsqrtf(var + 1e-5f);
  ss[c] = sc;
  ss[H_DIM + c] = beta[c] - mean * sc;
}

// ---------------- fused BN-apply + IndRNN recurrence (2 ch/thread) ----------------
__global__ __launch_bounds__(256) void bn_recur_kernel(
    const float* __restrict__ Z, const float* __restrict__ ss,
    const float* __restrict__ u, unsigned short* __restrict__ Hout) {
  int i2 = blockIdx.x * 256 + threadIdx.x;  // pair index, 0..BH/2-1
  int h0 = (i2 & (H_DIM / 2 - 1)) * 2;
  float sc0 = ss[h0], sc1 = ss[h0 + 1];
  float sh0 = ss[H_DIM + h0], sh1 = ss[H_DIM + h0 + 1];
  float u0 = u[h0], u1 = u[h0 + 1];
  float hv0 = 0.f, hv1 = 0.f;
#pragma unroll 4
  for (int t = 0; t < T_DIM; ++t) {
    float2 z = ((const float2*)Z)[(size_t)t * (BH_DIM / 2) + i2];
    float z0 = fmaf(z.x, sc0, sh0);
    float z1 = fmaf(z.y, sc1, sh1);
    hv0 = fmaxf(fmaf(u0, hv0, z0), 0.f);
    hv1 = fmaxf(fmaf(u1, hv1, z1), 0.f);
    ushort2 o; o.x = f2bf(hv0); o.y = f2bf(hv1);
    ((ushort2*)Hout)[(size_t)t * (BH_DIM / 2) + i2] = o;
  }
}

// ---------------- classifier ----------------
__global__ __launch_bounds__(256) void classifier_kernel(
    const unsigned short* __restrict__ hlast, const float* __restrict__ Wc,
    const float* __restrict__ bc, float* __restrict__ out) {
  __shared__ float hs[H_DIM];
  int b = blockIdx.y;
  int n = blockIdx.x * 256 + threadIdx.x;
  for (int k = threadIdx.x; k < H_DIM; k += 256)
    hs[k] = bf2f(hlast[(size_t)b * H_DIM + k]);
  __syncthreads();
  if (n < NC_DIM) {
    float acc = bc[n];
#pragma unroll 8
    for (int k = 0; k < H_DIM; ++k)
      acc = fmaf(hs[k], Wc[(size_t)k * NC_DIM + n], acc);
    out[(size_t)b * NC_DIM + n] = acc;
  }
}

extern "C" void kernel_launch(void* const* d_in, const int* in_sizes, int n_in,
                              void* d_out, int out_size, void* d_ws, size_t ws_size,
                              hipStream_t stream) {
  const float* x     = (const float*)d_in[0];
  const float* W     = (const float*)d_in[1];
  // d_in[2] = b: cancels under BatchNorm (shift-invariant)
  const float* gamma = (const float*)d_in[3];
  const float* beta  = (const float*)d_in[4];
  const float* u     = (const float*)d_in[5];
  const float* Wc    = (const float*)d_in[6];
  const float* bc    = (const float*)d_in[7];
  float* out = (float*)d_out;

  const size_t CH = (size_t)C_DIM * H_DIM;
  const size_t MH = (size_t)M_DIM * H_DIM;
  char* p = (char*)d_ws;
  unsigned short* Wt = (unsigned short*)p; p += L_DIM * CH * sizeof(unsigned short);
  unsigned short* Ha = (unsigned short*)p; p += MH * sizeof(unsigned short);
  unsigned short* Hb = (unsigned short*)p; p += MH * sizeof(unsigned short);
  float* Z    = (float*)p; p += MH * sizeof(float);
  float* psum = (float*)p; p += 128 * H_DIM * sizeof(float);
  float* psqs = (float*)p; p += 128 * H_DIM * sizeof(float);
  float* ss   = (float*)p; p += 2 * H_DIM * sizeof(float);

  f32_to_bf16_kernel<<<2048, 256, 0, stream>>>(x, Ha, (int)(MH / 4));
  wtrans_kernel<<<dim3(H_DIM / 32, C_DIM / 32, L_DIM), dim3(32, 8), 0, stream>>>(W, Wt);

  unsigned short* cur = Ha;
  unsigned short* nxt = Hb;
  for (int l = 0; l < L_DIM; ++l) {
    gemm_kernel<<<(M_DIM / 256) * (H_DIM / 256), 512, 131072, stream>>>(
        cur, Wt + (size_t)l * CH, Z, psum, psqs);
    bn_finalize_kernel<<<4, 256, 0, stream>>>(psum, psqs, gamma + (size_t)l * H_DIM,
                                              beta + (size_t)l * H_DIM, ss);
    bn_recur_kernel<<<BH_DIM / 512, 256, 0, stream>>>(Z, ss, u + (size_t)l * H_DIM, nxt);
    unsigned short* tmp = cur; cur = nxt; nxt = tmp;
  }
  classifier_kernel<<<dim3(4, B_DIM), 256, 0, stream>>>(
      cur + (size_t)(T_DIM - 1) * BH_DIM, Wc, bc, out);
}

// Round 3
// 782.030 us; speedup vs baseline: 1.6231x; 1.1349x over previous
//
#include <hip/hip_runtime.h>
#include <hip/hip_bf16.h>

#define T_DIM 256
#define B_DIM 128
#define C_DIM 1024
#define H_DIM 1024
#define L_DIM 6
#define NC_DIM 1000
#define M_DIM (T_DIM * B_DIM)    // 32768
#define BH_DIM (B_DIM * H_DIM)   // 131072

typedef __attribute__((ext_vector_type(8))) short bf16x8;
typedef __attribute__((ext_vector_type(4))) float f32x4;

__device__ __forceinline__ float bf2f(unsigned short u) {
  union { unsigned int i; float f; } v; v.i = ((unsigned int)u) << 16; return v.f;
}
__device__ __forceinline__ unsigned short f2bf(float f) {
  union { float f; unsigned int i; } v; v.f = f;
  unsigned int r = v.i + 0x7fffu + ((v.i >> 16) & 1u);  // RNE
  return (unsigned short)(r >> 16);
}

__device__ __forceinline__ void gload_lds16(const void* g, void* l) {
  __builtin_amdgcn_global_load_lds(
      (const __attribute__((address_space(1))) unsigned int*)g,
      (__attribute__((address_space(3))) unsigned int*)l, 16, 0, 0);
}

// ---------------- x f32 -> bf16 convert ----------------
__global__ __launch_bounds__(256) void f32_to_bf16_kernel(
    const float* __restrict__ in, unsigned short* __restrict__ out, int n4) {
  int stride = gridDim.x * blockDim.x;
  for (int i = blockIdx.x * blockDim.x + threadIdx.x; i < n4; i += stride) {
    float4 v = ((const float4*)in)[i];
    ushort4 o;
    o.x = f2bf(v.x); o.y = f2bf(v.y); o.z = f2bf(v.z); o.w = f2bf(v.w);
    ((ushort4*)out)[i] = o;
  }
}

// ---------------- W (L,C,H) f32 -> Wt (L,H,C) bf16 ----------------
__global__ __launch_bounds__(256) void wtrans_kernel(
    const float* __restrict__ W, unsigned short* __restrict__ Wt) {
  __shared__ float tile[32][33];
  int l = blockIdx.z;
  const float* Wl = W + (size_t)l * C_DIM * H_DIM;
  unsigned short* Wtl = Wt + (size_t)l * C_DIM * H_DIM;
  int h0 = blockIdx.x * 32, c0 = blockIdx.y * 32;
  int tx = threadIdx.x, ty = threadIdx.y;  // 32 x 8
#pragma unroll
  for (int i = 0; i < 32; i += 8)
    tile[ty + i][tx] = Wl[(size_t)(c0 + ty + i) * H_DIM + h0 + tx];
  __syncthreads();
#pragma unroll
  for (int i = 0; i < 32; i += 8)
    Wtl[(size_t)(h0 + ty + i) * C_DIM + c0 + tx] = f2bf(tile[tx][ty + i]);
}

// ---------------- GEMM 256x256 tile, BK=32, 4-buffer deep pipeline ----------------
// Z(bf16, M x H) = A(bf16, M x K) * Wt(bf16, N x K)^T, fused BN partial stats (f32-exact).
// 8 waves (2M x 4N), per-wave 128x64 output (8x4 16x16 frags).
// LDS: 4 buffers x (A 16KB + B 16KB) = 128 KiB.
// Swizzle: 16B-chunk ^= (row>>1)&3  ->  slot(=4*(row&1) + chunk^((row>>1)&3)) walks
// all 8 slots over 8 consecutive rows => 2-way bank aliasing (free) on ds_read_b128.
// Counted vmcnt(8): tiles t+2,t+3 stay in flight across the per-tile barrier.
#define NT 32  // K / 32

__global__ __launch_bounds__(512, 2) void gemm_kernel(
    const unsigned short* __restrict__ A, const unsigned short* __restrict__ Bt,
    unsigned short* __restrict__ Z, float* __restrict__ psum, float* __restrict__ psqs) {
  extern __shared__ char lds[];
  int bid = blockIdx.x;              // 512 blocks, %8==0 -> bijective XCD swizzle
  int swz = (bid & 7) * 64 + (bid >> 3);
  int tm = swz >> 2, tn = swz & 3;   // 128 x 4 tiles
  int tid = threadIdx.x;
  int wv = tid >> 6, ln = tid & 63;
  int wm = wv >> 2, wn = wv & 3;     // 2 x 4 wave grid

  // ---- staging precompute (pre-swizzled global source, linear LDS dest) ----
  const char* Asrc = (const char*)A + (size_t)tm * 256 * 2048;   // row stride 2048B
  const char* Bsrc = (const char*)Bt + (size_t)tn * 256 * 2048;
  int p0 = wv * 1024 + ln * 16;          // physical byte (load 0)
  int p1 = 8192 + wv * 1024 + ln * 16;   // physical byte (load 1)
  int l0 = p0 ^ (((p0 >> 7) & 3) << 4);  // involution: chunk ^= (row>>1)&3
  int l1 = p1 ^ (((p1 >> 7) & 3) << 4);
  int ro0 = (p0 >> 6) * 2048 + (l0 & 63);  // panel byte offset sans k-term
  int ro1 = (p1 >> 6) * 2048 + (l1 & 63);
  int dst0 = wv * 1024;         // wave-uniform LDS dest bases (+ lane*16 by HW)
  int dst1 = 8192 + wv * 1024;

  // swizzled ds_read lane offset: row s=(ln&15), chunk=(ln>>4)^((s>>1)&3)
  int laneoff = (ln & 15) * 64 + ((((ln >> 4) ^ ((ln & 15) >> 1)) & 3) << 4);

  f32x4 acc[8][4];
  f32x4 zero = {0.f, 0.f, 0.f, 0.f};
#pragma unroll
  for (int m = 0; m < 8; ++m)
#pragma unroll
    for (int n = 0; n < 4; ++n) acc[m][n] = zero;

  auto stage = [&](int t) {
    char* ldsb = lds + ((t & 3) * 32768);
    int ko = t * 64;
    gload_lds16(Asrc + ro0 + ko, ldsb + dst0);
    gload_lds16(Asrc + ro1 + ko, ldsb + dst1);
    gload_lds16(Bsrc + ro0 + ko, ldsb + 16384 + dst0);
    gload_lds16(Bsrc + ro1 + ko, ldsb + 16384 + dst1);
  };

  auto body = [&](int t, bool dostage) {
    const char* buf = lds + ((t & 3) * 32768);
    const char* Ab = buf + wm * 8192;
    const char* Bb = buf + 16384 + wn * 4096;
    bf16x8 bf[4], a0[4], a1[4];
#pragma unroll
    for (int n = 0; n < 4; ++n) bf[n] = *(const bf16x8*)(Bb + n * 1024 + laneoff);
#pragma unroll
    for (int m = 0; m < 4; ++m) a0[m] = *(const bf16x8*)(Ab + m * 1024 + laneoff);
#pragma unroll
    for (int m = 0; m < 4; ++m) a1[m] = *(const bf16x8*)(Ab + 4096 + m * 1024 + laneoff);
    if (dostage) stage(t + 3);
    __builtin_amdgcn_s_setprio(1);
#pragma unroll
    for (int m = 0; m < 4; ++m)
#pragma unroll
      for (int n = 0; n < 4; ++n)
        acc[m][n] = __builtin_amdgcn_mfma_f32_16x16x32_bf16(a0[m], bf[n], acc[m][n], 0, 0, 0);
#pragma unroll
    for (int m = 0; m < 4; ++m)
#pragma unroll
      for (int n = 0; n < 4; ++n)
        acc[m + 4][n] = __builtin_amdgcn_mfma_f32_16x16x32_bf16(a1[m], bf[n], acc[m + 4][n], 0, 0, 0);
    __builtin_amdgcn_s_setprio(0);
  };

  // prologue: tiles 0,1,2 in flight (12 loads); wait tile0 (vmcnt 8 = tiles 1,2)
  stage(0); stage(1); stage(2);
  asm volatile("s_waitcnt vmcnt(8)" ::: "memory");
  __builtin_amdgcn_s_barrier();

  for (int t = 0; t < NT - 3; ++t) {   // t = 0..28, stages t+3 <= 31
    body(t, true);
    asm volatile("s_waitcnt vmcnt(8)" ::: "memory");  // tiles t+2,t+3 stay in flight
    __builtin_amdgcn_s_barrier();
  }
  body(NT - 3, false);
  asm volatile("s_waitcnt vmcnt(4)" ::: "memory");
  __builtin_amdgcn_s_barrier();
  body(NT - 2, false);
  asm volatile("s_waitcnt vmcnt(0)" ::: "memory");
  __builtin_amdgcn_s_barrier();
  body(NT - 1, false);

  // ---- epilogue: fused BN partial stats (exact f32) + bf16 Z write ----
  // C/D layout: col = ln&15, row = (ln>>4)*4 + reg
  float s[4], q[4];
#pragma unroll
  for (int n = 0; n < 4; ++n) {
    float sv = 0.f, qv = 0.f;
#pragma unroll
    for (int m = 0; m < 8; ++m)
#pragma unroll
      for (int r = 0; r < 4; ++r) {
        float v = acc[m][n][r];
        sv += v; qv += v * v;
      }
    s[n] = sv; q[n] = qv;
  }
#pragma unroll
  for (int n = 0; n < 4; ++n) {
    s[n] += __shfl_xor(s[n], 16); s[n] += __shfl_xor(s[n], 32);
    q[n] += __shfl_xor(q[n], 16); q[n] += __shfl_xor(q[n], 32);
  }
  float* red = (float*)lds;  // buffer 0 region (dead after K-loop barriers)
  if (ln < 16) {
#pragma unroll
    for (int n = 0; n < 4; ++n) {
      red[wm * 256 + wn * 64 + n * 16 + ln] = s[n];
      red[512 + wm * 256 + wn * 64 + n * 16 + ln] = q[n];
    }
  }
  __syncthreads();
  if (tid < 256) {
    psum[(size_t)tm * H_DIM + tn * 256 + tid] = red[tid] + red[256 + tid];
  } else {
    int c = tid - 256;
    psqs[(size_t)tm * H_DIM + tn * 256 + c] = red[512 + c] + red[768 + c];
  }
  // bf16 Z stores
  int r0 = tm * 256 + wm * 128 + ((ln >> 4) << 2);
  int c0 = tn * 256 + wn * 64 + (ln & 15);
#pragma unroll
  for (int m = 0; m < 8; ++m)
#pragma unroll
    for (int n = 0; n < 4; ++n) {
      unsigned short* zp = Z + (size_t)(r0 + m * 16) * H_DIM + c0 + n * 16;
#pragma unroll
      for (int r = 0; r < 4; ++r) zp[(size_t)r * H_DIM] = f2bf(acc[m][n][r]);
    }
}

// ---------------- BN finalize: sum 128 partials per channel ----------------
__global__ __launch_bounds__(256) void bn_finalize_kernel(
    const float* __restrict__ psum, const float* __restrict__ psqs,
    const float* __restrict__ gamma, const float* __restrict__ beta,
    float* __restrict__ ss) {
  int c = blockIdx.x * blockDim.x + threadIdx.x;
  float s = 0.f, q = 0.f;
  for (int i = 0; i < 128; ++i) {
    s += psum[(size_t)i * H_DIM + c];
    q += psqs[(size_t)i * H_DIM + c];
  }
  const float invN = 1.0f / (float)M_DIM;
  float mean = s * invN;
  float var = q * invN - mean * mean;
  float sc = gamma[c] * rsqrtf(var + 1e-5f);
  ss[c] = sc;
  ss[H_DIM + c] = beta[c] - mean * sc;
}

// ---------------- fused BN-apply + IndRNN recurrence (2 ch/thread, bf16 Z) ----------------
__global__ __launch_bounds__(256) void bn_recur_kernel(
    const unsigned short* __restrict__ Z, const float* __restrict__ ss,
    const float* __restrict__ u, unsigned short* __restrict__ Hout) {
  int i2 = blockIdx.x * 256 + threadIdx.x;  // pair index, 0..BH/2-1
  int h0 = (i2 & (H_DIM / 2 - 1)) * 2;
  float sc0 = ss[h0], sc1 = ss[h0 + 1];
  float sh0 = ss[H_DIM + h0], sh1 = ss[H_DIM + h0 + 1];
  float u0 = u[h0], u1 = u[h0 + 1];
  float hv0 = 0.f, hv1 = 0.f;
  const unsigned int* Zp = (const unsigned int*)Z;
#pragma unroll 8
  for (int t = 0; t < T_DIM; ++t) {
    unsigned int zz = Zp[(size_t)t * (BH_DIM / 2) + i2];
    float z0 = fmaf(bf2f((unsigned short)(zz & 0xffffu)), sc0, sh0);
    float z1 = fmaf(bf2f((unsigned short)(zz >> 16)), sc1, sh1);
    hv0 = fmaxf(fmaf(u0, hv0, z0), 0.f);
    hv1 = fmaxf(fmaf(u1, hv1, z1), 0.f);
    ushort2 o; o.x = f2bf(hv0); o.y = f2bf(hv1);
    ((ushort2*)Hout)[(size_t)t * (BH_DIM / 2) + i2] = o;
  }
}

// ---------------- classifier ----------------
__global__ __launch_bounds__(256) void classifier_kernel(
    const unsigned short* __restrict__ hlast, const float* __restrict__ Wc,
    const float* __restrict__ bc, float* __restrict__ out) {
  __shared__ float hs[H_DIM];
  int b = blockIdx.y;
  int n = blockIdx.x * 256 + threadIdx.x;
  for (int k = threadIdx.x; k < H_DIM; k += 256)
    hs[k] = bf2f(hlast[(size_t)b * H_DIM + k]);
  __syncthreads();
  if (n < NC_DIM) {
    float acc = bc[n];
#pragma unroll 8
    for (int k = 0; k < H_DIM; ++k)
      acc = fmaf(hs[k], Wc[(size_t)k * NC_DIM + n], acc);
    out[(size_t)b * NC_DIM + n] = acc;
  }
}

extern "C" void kernel_launch(void* const* d_in, const int* in_sizes, int n_in,
                              void* d_out, int out_size, void* d_ws, size_t ws_size,
                              hipStream_t stream) {
  const float* x     = (const float*)d_in[0];
  const float* W     = (const float*)d_in[1];
  // d_in[2] = b: cancels under BatchNorm (shift-invariant)
  const float* gamma = (const float*)d_in[3];
  const float* beta  = (const float*)d_in[4];
  const float* u     = (const float*)d_in[5];
  const float* Wc    = (const float*)d_in[6];
  const float* bc    = (const float*)d_in[7];
  float* out = (float*)d_out;

  const size_t CH = (size_t)C_DIM * H_DIM;
  const size_t MH = (size_t)M_DIM * H_DIM;
  char* p = (char*)d_ws;
  unsigned short* Wt = (unsigned short*)p; p += L_DIM * CH * sizeof(unsigned short);
  unsigned short* Ha = (unsigned short*)p; p += MH * sizeof(unsigned short);
  unsigned short* Hb = (unsigned short*)p; p += MH * sizeof(unsigned short);
  unsigned short* Z  = (unsigned short*)p; p += MH * sizeof(unsigned short);
  float* psum = (float*)p; p += 128 * H_DIM * sizeof(float);
  float* psqs = (float*)p; p += 128 * H_DIM * sizeof(float);
  float* ss   = (float*)p; p += 2 * H_DIM * sizeof(float);

  f32_to_bf16_kernel<<<2048, 256, 0, stream>>>(x, Ha, (int)(MH / 4));
  wtrans_kernel<<<dim3(H_DIM / 32, C_DIM / 32, L_DIM), dim3(32, 8), 0, stream>>>(W, Wt);

  unsigned short* cur = Ha;
  unsigned short* nxt = Hb;
  for (int l = 0; l < L_DIM; ++l) {
    gemm_kernel<<<(M_DIM / 256) * (H_DIM / 256), 512, 131072, stream>>>(
        cur, Wt + (size_t)l * CH, Z, psum, psqs);
    bn_finalize_kernel<<<4, 256, 0, stream>>>(psum, psqs, gamma + (size_t)l * H_DIM,
                                              beta + (size_t)l * H_DIM, ss);
    bn_recur_kernel<<<BH_DIM / 512, 256, 0, stream>>>(Z, ss, u + (size_t)l * H_DIM, nxt);
    unsigned short* tmp = cur; cur = nxt; nxt = tmp;
  }
  classifier_kernel<<<dim3(4, B_DIM), 256, 0, stream>>>(
      cur + (size_t)(T_DIM - 1) * BH_DIM, Wc, bc, out);
}